// Round 1
// baseline (136.721 us; speedup 1.0000x reference)
//
#include <hip/hip_runtime.h>
#include <stdint.h>

#define NQ   8192
#define NB   2
#define KNN  10
#define K1   11                 // top-11 incl. self (d=0); self dropped in loss
#define NTOT (NB * NQ)
#define NGRP (NTOT / 64)        // 256 blocks, one per 64-query group, 1/CU
#define IDXMASK 0x1FFFu

// tau: per query, 11th-smallest distance over fixed 2048-point subsample (stride 4)
#define SUBS    2048
#define SSTRIDE 4
#define TW      16              // 16 waves (1024 threads)
#define CKI(s, c, lane) (((s) * TW + (c)) * 64 + (lane))

// scan: each wave scans a contiguous 512-candidate chunk for all 64 queries
#define CPW   (NQ / TW)         // 512
// shared per-query survivor lists, aliased over tau scratch.
// lambda ~= 44 survivors/query (11/2048 quantile over 8192); CAP=176 => P(ovf) ~ 0
#define LSTR  177               // odd stride -> conflict-free strided access
#define CAP   176

static __device__ __forceinline__ uint32_t umin32(uint32_t a, uint32_t b) { return a < b ? a : b; }
static __device__ __forceinline__ uint32_t umax32(uint32_t a, uint32_t b) { return a > b ? a : b; }

static __device__ __forceinline__ void insert11(uint32_t (&l)[K1], uint32_t key) {
#pragma unroll
    for (int s = 0; s < K1; ++s) {
        const uint32_t m = l[s];
        l[s] = umin32(key, m);
        key  = umax32(key, m);
    }
}

// ---------------- fused: stage cloud -> tau -> filtered scan -> merge -> loss ----------------
__global__ __launch_bounds__(1024, 4) void plap_fused(
    const float* __restrict__ p1, const float* __restrict__ p2,
    float* __restrict__ partial)
{
    __shared__ float2   sxy[NQ];            // 64 KB  whole-cloud xy
    __shared__ float    szz[NQ];            // 32 KB  whole-cloud z
    __shared__ uint32_t ckls[64 * LSTR];    // 45.3 KB: tau merge scratch, then survivor lists
    __shared__ uint32_t cnt[64];
    __shared__ uint32_t tauS[64];           // total ~144.1 KB < 160 KB -> 1 block/CU

    const int tid  = threadIdx.x;
    const int lane = tid & 63;
    const int wave = tid >> 6;
    const int wq   = __builtin_amdgcn_readfirstlane(wave);
    const int b    = blockIdx.x >> 7;
    const int q0   = (blockIdx.x & 127) << 6;
    const int qi   = q0 | lane;
    const float* __restrict__ P  = p1 + (size_t)b * NQ * 3;
    const float* __restrict__ P2 = p2 + (size_t)b * NQ * 3;

    // ---- stage the whole batch cloud into LDS (96 KB, L2-resident source) ----
#pragma unroll
    for (int t = tid; t < NQ; t += 1024) {
        const float* src = P + (size_t)t * 3;
        sxy[t] = make_float2(src[0], src[1]);
        szz[t] = src[2];
    }
    __syncthreads();

    const float qx = sxy[qi].x, qy = sxy[qi].y, qz = szz[qi];

    // ---- tau phase: per-wave top-11 of 128 subsamples (raw distance bits, no index) ----
    uint32_t l[K1];
#pragma unroll
    for (int s = 0; s < K1; ++s) l[s] = 0xFFFFFFFFu;
    const int t0 = wq * (SUBS / TW);
#pragma unroll 4
    for (int t = t0; t < t0 + SUBS / TW; ++t) {
        const int j = t * SSTRIDE;
        const float2 cc = sxy[j];                      // broadcast ds_read
        const float dx = qx - cc.x, dy = qy - cc.y, dz = qz - szz[j];
        const float d  = fmaf(dx, dx, fmaf(dy, dy, dz * dz));
        insert11(l, __float_as_uint(d));
    }
#pragma unroll
    for (int s = 0; s < K1; ++s) ckls[CKI(s, wq, lane)] = l[s];
    __syncthreads();

    for (int st = 1; st < TW; st <<= 1) {              // tree-merge -> 11th of 2048
        if ((wq & (2 * st - 1)) == 0) {
            uint32_t A[K1];
#pragma unroll
            for (int s = 0; s < K1; ++s) A[s] = ckls[CKI(s, wq, lane)];
#pragma unroll
            for (int e = 0; e < K1; ++e) insert11(A, ckls[CKI(e, wq + st, lane)]);
            if (2 * st < TW) {
#pragma unroll
                for (int s = 0; s < K1; ++s) ckls[CKI(s, wq, lane)] = A[s];
            } else {
                tauS[lane] = A[K1 - 1];
            }
        }
        __syncthreads();
    }

    const float tauUpF = __uint_as_float(tauS[lane] | IDXMASK); // trunc-space superset bound
    if (tid < 64) cnt[tid] = 0;
    __syncthreads();                                   // also fences ckls reuse as lists

    // ---- scan phase: filter 512 candidates/wave against per-query tau ----
    const int c0 = wq * CPW;
#pragma unroll 8
    for (int t = 0; t < CPW; ++t) {
        const int c = c0 + t;
        const float2 cc = sxy[c];                      // broadcast ds_read_b64
        const float dx = qx - cc.x;
        const float dy = qy - cc.y;
        const float dz = qz - szz[c];
        const float d  = fmaf(dx, dx, fmaf(dy, dy, dz * dz));
        if (d <= tauUpF) {
            const uint32_t key = (__float_as_uint(d) & ~IDXMASK) | (uint32_t)c;
            const uint32_t old = atomicAdd(&cnt[lane], 1u);
            if (old < CAP) ckls[lane * LSTR + old] = key;
        }
    }
    __syncthreads();

    // ---- merge + loss: wave 0, lane = query ----
    if (wq == 0) {
        uint32_t F[K1];
#pragma unroll
        for (int s = 0; s < K1; ++s) F[s] = 0xFFFFFFFFu;
        const uint32_t c = cnt[lane];
        if (c <= CAP) {
            for (uint32_t s = 0; s < c; ++s) insert11(F, ckls[lane * LSTR + s]);
        } else {
            // exact fallback (P ~ 0): full rescan from LDS
            for (int j = 0; j < NQ; ++j) {
                const float2 cc = sxy[j];
                const float dx = qx - cc.x, dy = qy - cc.y, dz = qz - szz[j];
                const float d  = fmaf(dx, dx, fmaf(dy, dy, dz * dz));
                insert11(F, (__float_as_uint(d) & ~IDXMASK) | (uint32_t)j);
            }
        }

        float s1x = 0.f, s1y = 0.f, s1z = 0.f, s2x = 0.f, s2y = 0.f, s2z = 0.f;
#pragma unroll
        for (int s = 1; s < K1; ++s) {                 // F[0] = self (d = 0)
            const int n = (int)(F[s] & IDXMASK);
            const float2 nn = sxy[n];                  // p1 gather from LDS
            s1x += nn.x; s1y += nn.y; s1z += szz[n];
            s2x += P2[n * 3 + 0]; s2y += P2[n * 3 + 1]; s2z += P2[n * 3 + 2];
        }
        const float invk = 1.0f / (float)KNN;
        const float lx = (s1x * invk - qx) - (s2x * invk - P2[qi * 3 + 0]);
        const float ly = (s1y * invk - qy) - (s2y * invk - P2[qi * 3 + 1]);
        const float lz = (s1z * invk - qz) - (s2z * invk - P2[qi * 3 + 2]);
        float acc = fabsf(lx) + fabsf(ly) + fabsf(lz);
#pragma unroll
        for (int off = 32; off > 0; off >>= 1)
            acc += __shfl_down(acc, off, 64);
        if (lane == 0) partial[blockIdx.x] = acc;      // deterministic, no atomics
    }
}

// ---------------- tiny deterministic reduction over 256 block partials ----------------
__global__ __launch_bounds__(64) void plap_reduce(
    const float* __restrict__ partial, float* __restrict__ out)
{
    const int t = threadIdx.x;
    float a = partial[t] + partial[t + 64] + partial[t + 128] + partial[t + 192];
#pragma unroll
    for (int off = 32; off > 0; off >>= 1)
        a += __shfl_down(a, off, 64);
    if (t == 0) out[0] = a * (1.0f / (float)(NTOT * 3));
}

extern "C" void kernel_launch(void* const* d_in, const int* in_sizes, int n_in,
                              void* d_out, int out_size, void* d_ws, size_t ws_size,
                              hipStream_t stream) {
    const float* p1 = (const float*)d_in[0];
    const float* p2 = (const float*)d_in[1];
    float* out      = (float*)d_out;
    float* partial  = (float*)d_ws;                    // 256 floats, fully rewritten each run

    plap_fused <<<dim3(NGRP), dim3(TW * 64), 0, stream>>>(p1, p2, partial);
    plap_reduce<<<dim3(1),    dim3(64),      0, stream>>>(partial, out);
}

// Round 2
// 133.812 us; speedup vs baseline: 1.0217x; 1.0217x over previous
//
#include <hip/hip_runtime.h>
#include <stdint.h>

#define NQ   8192
#define NB   2
#define KNN  10
#define K1   11                 // top-11 incl. self (d=0); self dropped in loss
#define NTOT (NB * NQ)
#define NGRP (NTOT / 64)        // 256 blocks, one per 64-query group, 1/CU
#define IDXMASK 0x1FFFu

// tau: per query, 11th-smallest distance over fixed 2048-point subsample (stride 4)
#define SUBS    2048
#define SSTRIDE 4
#define TW      16              // 16 waves (1024 threads)
#define CPW     (NQ / TW)       // 512 candidates per wave chunk
#define CKI(s, c, lane) (((s) * TW + (c)) * 64 + (lane))

// private survivor list per (wave,lane): lambda ~= 44/16 = 2.75, CAP=14 -> P(ovf) ~1e-6/cell
// exact per-thread fallback on overflow keeps the kernel exact unconditionally.
#define CAP   14

static __device__ __forceinline__ uint32_t umin32(uint32_t a, uint32_t b) { return a < b ? a : b; }
static __device__ __forceinline__ uint32_t umax32(uint32_t a, uint32_t b) { return a > b ? a : b; }

static __device__ __forceinline__ void insert11(uint32_t (&l)[K1], uint32_t key) {
#pragma unroll
    for (int s = 0; s < K1; ++s) {
        const uint32_t m = l[s];
        l[s] = umin32(key, m);
        key  = umax32(key, m);
    }
}

// ---------------- fused: stage cloud -> tau -> private-list scan -> parallel merge -> loss ----------------
__global__ __launch_bounds__(1024, 4) void plap_fused(
    const float* __restrict__ p1, const float* __restrict__ p2,
    float* __restrict__ partial)
{
    __shared__ float2   sxy[NQ];            // 64 KB  whole-cloud xy
    __shared__ float    szz[NQ];            // 32 KB  whole-cloud z
    __shared__ uint32_t ckls[TW * 64 * CAP];// 56 KB: tau tree scratch (44 KB) / private lists / merge scratch
    __shared__ uint32_t tauS[64];           // total ~152.2 KB -> 1 block/CU

    const int tid  = threadIdx.x;
    const int lane = tid & 63;
    const int wave = tid >> 6;
    const int wq   = __builtin_amdgcn_readfirstlane(wave);
    const int b    = blockIdx.x >> 7;
    const int q0   = (blockIdx.x & 127) << 6;
    const int qi   = q0 | lane;
    const float* __restrict__ P  = p1 + (size_t)b * NQ * 3;
    const float* __restrict__ P2 = p2 + (size_t)b * NQ * 3;

    // ---- stage the whole batch cloud into LDS (96 KB, L2-resident source) ----
#pragma unroll
    for (int t = tid; t < NQ; t += 1024) {
        const float* src = P + (size_t)t * 3;
        sxy[t] = make_float2(src[0], src[1]);
        szz[t] = src[2];
    }
    __syncthreads();

    const float qx = sxy[qi].x, qy = sxy[qi].y, qz = szz[qi];

    // ---- tau: per-wave top-11 of 128 subsamples (raw distance bits), tree-merge 16->1 ----
    {
        uint32_t l[K1];
#pragma unroll
        for (int s = 0; s < K1; ++s) l[s] = 0xFFFFFFFFu;
        const int t0 = wq * (SUBS / TW);
#pragma unroll 4
        for (int t = t0; t < t0 + SUBS / TW; ++t) {
            const int j = t * SSTRIDE;
            const float2 cc = sxy[j];                  // broadcast ds_read
            const float dx = qx - cc.x, dy = qy - cc.y, dz = qz - szz[j];
            const float d  = fmaf(dx, dx, fmaf(dy, dy, dz * dz));
            insert11(l, __float_as_uint(d));
        }
#pragma unroll
        for (int s = 0; s < K1; ++s) ckls[CKI(s, wq, lane)] = l[s];
        for (int st = 1; st < TW; st <<= 1) {
            __syncthreads();
            if ((wq & (2 * st - 1)) == 0) {
#pragma unroll
                for (int e = 0; e < K1; ++e) insert11(l, ckls[CKI(e, wq + st, lane)]);
                if (2 * st < TW) {
#pragma unroll
                    for (int s = 0; s < K1; ++s) ckls[CKI(s, wq, lane)] = l[s];
                } else {
                    tauS[lane] = l[K1 - 1];
                }
            }
        }
        __syncthreads();                               // tree reads done; ckls reusable as lists
    }

    const float tauUpF = __uint_as_float(tauS[lane] | IDXMASK); // trunc-space superset bound

    // ---- scan: private per-(wave,lane) list, register counter, NO atomics ----
    uint32_t myCnt = 0;
    const uint32_t lbase = (uint32_t)(wq * 64 + lane) * CAP;
    const int c0 = wq * CPW;
#pragma unroll 8
    for (int t = 0; t < CPW; ++t) {
        const int c = c0 + t;
        const float2 cc = sxy[c];                      // broadcast ds_read_b64
        const float dx = qx - cc.x;
        const float dy = qy - cc.y;
        const float dz = qz - szz[c];
        const float d  = fmaf(dx, dx, fmaf(dy, dy, dz * dz));
        if (d <= tauUpF) {
            const uint32_t key = (__float_as_uint(d) & ~IDXMASK) | (uint32_t)c;
            if (myCnt < CAP) ckls[lbase + myCnt] = key;
            myCnt++;
        }
    }

    // ---- merge-A: every thread reduces its own list to top-11 in regs ----
    uint32_t F[K1];
#pragma unroll
    for (int s = 0; s < K1; ++s) F[s] = 0xFFFFFFFFu;
    if (myCnt <= CAP) {
        for (uint32_t s = 0; s < myCnt; ++s) insert11(F, ckls[lbase + s]);
    } else {
        // exact fallback (P ~ 1e-6 per cell): rescan own 512-chunk from LDS
        for (int t = 0; t < CPW; ++t) {
            const int c = c0 + t;
            const float2 cc = sxy[c];
            const float dx = qx - cc.x, dy = qy - cc.y, dz = qz - szz[c];
            const float d  = fmaf(dx, dx, fmaf(dy, dy, dz * dz));
            if (d <= tauUpF)
                insert11(F, (__float_as_uint(d) & ~IDXMASK) | (uint32_t)c);
        }
    }
    __syncthreads();                                   // all list reads done before scratch overwrite

    // ---- tree merge 16 -> 1 (all waves active first stage) ----
#pragma unroll
    for (int s = 0; s < K1; ++s) ckls[CKI(s, wq, lane)] = F[s];
    for (int st = 1; st < TW; st <<= 1) {
        __syncthreads();
        if ((wq & (2 * st - 1)) == 0) {
#pragma unroll
            for (int e = 0; e < K1; ++e) insert11(F, ckls[CKI(e, wq + st, lane)]);
            if (2 * st < TW) {
#pragma unroll
                for (int s = 0; s < K1; ++s) ckls[CKI(s, wq, lane)] = F[s];
            }
        }
    }

    // ---- loss: wave 0, lane = query ----
    if (wq == 0) {
        float s1x = 0.f, s1y = 0.f, s1z = 0.f, s2x = 0.f, s2y = 0.f, s2z = 0.f;
#pragma unroll
        for (int s = 1; s < K1; ++s) {                 // F[0] = self (d = 0)
            const int n = (int)(F[s] & IDXMASK);
            const float2 nn = sxy[n];                  // p1 gather from LDS
            s1x += nn.x; s1y += nn.y; s1z += szz[n];
            s2x += P2[n * 3 + 0]; s2y += P2[n * 3 + 1]; s2z += P2[n * 3 + 2];
        }
        const float invk = 1.0f / (float)KNN;
        const float lx = (s1x * invk - qx) - (s2x * invk - P2[qi * 3 + 0]);
        const float ly = (s1y * invk - qy) - (s2y * invk - P2[qi * 3 + 1]);
        const float lz = (s1z * invk - qz) - (s2z * invk - P2[qi * 3 + 2]);
        float acc = fabsf(lx) + fabsf(ly) + fabsf(lz);
#pragma unroll
        for (int off = 32; off > 0; off >>= 1)
            acc += __shfl_down(acc, off, 64);
        if (lane == 0) partial[blockIdx.x] = acc;      // deterministic, no atomics
    }
}

// ---------------- tiny deterministic reduction over 256 block partials ----------------
__global__ __launch_bounds__(64) void plap_reduce(
    const float* __restrict__ partial, float* __restrict__ out)
{
    const int t = threadIdx.x;
    float a = partial[t] + partial[t + 64] + partial[t + 128] + partial[t + 192];
#pragma unroll
    for (int off = 32; off > 0; off >>= 1)
        a += __shfl_down(a, off, 64);
    if (t == 0) out[0] = a * (1.0f / (float)(NTOT * 3));
}

extern "C" void kernel_launch(void* const* d_in, const int* in_sizes, int n_in,
                              void* d_out, int out_size, void* d_ws, size_t ws_size,
                              hipStream_t stream) {
    const float* p1 = (const float*)d_in[0];
    const float* p2 = (const float*)d_in[1];
    float* out      = (float*)d_out;
    float* partial  = (float*)d_ws;                    // 256 floats, fully rewritten each run

    plap_fused <<<dim3(NGRP), dim3(TW * 64), 0, stream>>>(p1, p2, partial);
    plap_reduce<<<dim3(1),    dim3(64),      0, stream>>>(partial, out);
}